// Round 2
// baseline (1028.601 us; speedup 1.0000x reference)
//
#include <hip/hip_runtime.h>
#include <hip/hip_fp16.h>

// Problem dims (fixed): B=64, N=T=64, L=128, H=256, V=256, G=3H=768
typedef _Float16 f16;
typedef _Float16 f16x2 __attribute__((ext_vector_type(2)));
typedef unsigned int u32;

#define DEV static __device__ __forceinline__

DEV float dot2f(u32 a, u32 b, float c) {
#if __has_builtin(__builtin_amdgcn_fdot2)
    return __builtin_amdgcn_fdot2(__builtin_bit_cast(f16x2, a),
                                  __builtin_bit_cast(f16x2, b), c, false);
#else
    f16x2 x = __builtin_bit_cast(f16x2, a), y = __builtin_bit_cast(f16x2, b);
    return c + (float)x[0] * (float)y[0] + (float)x[1] * (float)y[1];
#endif
}

DEV float rcp_fast(float x) {
#if __has_builtin(__builtin_amdgcn_rcpf)
    return __builtin_amdgcn_rcpf(x);
#else
    return 1.f / x;
#endif
}
DEV float sigmoid_f(float x) { return rcp_fast(1.f + __expf(-x)); }
DEV float tanh_f(float x)    { return 1.f - 2.f * rcp_fast(1.f + __expf(2.f * x)); }

DEV u32 addrelu2(u32 a, u32 b) {  // fp16x2 (a+b) then relu
    f16x2 x = __builtin_bit_cast(f16x2, a) + __builtin_bit_cast(f16x2, b);
    f16x2 z = {};
    x = __builtin_elementwise_max(x, z);
    return __builtin_bit_cast(u32, x);
}

// ---------------- workspace layout (bytes) ----------------
#define WS_GXT0  0u          // 256*768 f16 token->gate table (layer0, biases folded)
#define WS_WHH0  393216u     // 768*256 f16
#define WS_WHH1  786432u
#define WS_WIH1  1179648u
#define WS_NHW1  1572864u    // 256*256 f16
#define WS_NHW2  1703936u
#define WS_SHW1  1835008u    // 128*256 f16
#define WS_SHW2  1900544u    // 128 f16
#define WS_EHW2  1900800u    // 256 f16
#define WS_WKC   1901312u    // 256*256 f16 combined W1k@ek_W
#define WS_WQC   2032384u
#define WS_BKC   2163456u    // 256 f32 (includes eh_b1)
#define WS_BQC   2164480u
#define WS_H0    2165504u    // 64*256 f32
#define WS_H1    2231040u    // 64*64*256 f16, (t,b,c)
#define WS_GX1   4328192u    // 4096*768 f16, (t*64+b, g)
#define WS_HID   10619648u   // 64*64*256 f16, (b,t,c)
#define WS_HK    12716800u   // 4096*256 f16
#define WS_HQ    14813952u

// ---------------- fp32 -> fp16 weight conversion ----------------
struct ConvArgs { const float* src[8]; f16* dst[8]; int cnt[8]; };

__global__ void k_convert(ConvArgs a) {
    int idx = blockIdx.x * 256 + threadIdx.x;
#pragma unroll
    for (int s = 0; s < 8; s++) {
        if (idx < a.cnt[s]) { a.dst[s][idx] = (f16)a.src[s][idx]; return; }
        idx -= a.cnt[s];
    }
}

// ---------------- gxt0 table: emb @ Wih0.T + bih0 (+bhh0 for r,z) ----------------
__global__ __launch_bounds__(256) void k_gxt0(const float* emb, const float* wih0,
                                              const float* bih0, const float* bhh0,
                                              f16* gxt0) {
    int v = blockIdx.x, tid = threadIdx.x;
    __shared__ float es[256];
    es[tid] = emb[v * 256 + tid];
    __syncthreads();
#pragma unroll
    for (int p = 0; p < 3; p++) {
        int g = tid + p * 256;
        const float4* w = (const float4*)(wih0 + g * 256);
        float acc = bih0[g] + (g < 512 ? bhh0[g] : 0.f);
        for (int k = 0; k < 64; k++) {
            float4 wv = w[k];
            acc += es[4*k]*wv.x + es[4*k+1]*wv.y + es[4*k+2]*wv.z + es[4*k+3]*wv.w;
        }
        gxt0[v * 768 + g] = (f16)acc;
    }
}

// ---------------- h0 = relu(z@W1.T+b1)@W2.T+b2 ----------------
__global__ __launch_bounds__(256) void k_h0(const float* z, const float* w1, const float* b1,
                                            const float* w2, const float* b2, float* h0) {
    int b = blockIdx.x, tid = threadIdx.x;
    __shared__ float zs[128];
    __shared__ float t1[256];
    if (tid < 128) zs[tid] = z[b * 128 + tid];
    __syncthreads();
    const float4* w = (const float4*)(w1 + tid * 128);
    float acc = b1[tid];
    for (int k = 0; k < 32; k++) {
        float4 wv = w[k];
        acc += zs[4*k]*wv.x + zs[4*k+1]*wv.y + zs[4*k+2]*wv.z + zs[4*k+3]*wv.w;
    }
    t1[tid] = fmaxf(acc, 0.f);
    __syncthreads();
    const float4* ww = (const float4*)(w2 + tid * 256);
    float a2 = b2[tid];
    for (int k = 0; k < 64; k++) {
        float4 wv = ww[k];
        a2 += t1[4*k]*wv.x + t1[4*k+1]*wv.y + t1[4*k+2]*wv.z + t1[4*k+3]*wv.w;
    }
    h0[b * 256 + tid] = a2;
}

// ---------------- combined edge weights: Wk_c = W1k@ek_W etc ----------------
__global__ __launch_bounds__(256) void k_wkq(const float* ehW1, const float* ekW, const float* eqW,
                                             const float* ekb, const float* eqb, const float* ehb1,
                                             f16* wkc, f16* wqc, float* bkc, float* bqc) {
    int blk = blockIdx.x, which = blk >> 8, o = blk & 255, tid = threadIdx.x;
    __shared__ float w1s[256];
    w1s[tid] = ehW1[o * 512 + (which ? 256 : 0) + tid];
    __syncthreads();
    const float* m = which ? eqW : ekW;
    float acc = 0.f;
    for (int mm = 0; mm < 256; mm++) acc += w1s[mm] * m[mm * 256 + tid];
    (which ? wqc : wkc)[o * 256 + tid] = (f16)acc;
    if (tid == 0) {
        const float* bb = which ? eqb : ekb;
        float s = which ? 0.f : ehb1[o];   // fold eh_b1 into k-side bias
        for (int mm = 0; mm < 256; mm++) s += w1s[mm] * bb[mm];
        (which ? bqc : bkc)[o] = s;
    }
}

// ---------------- GRU layer: 1 WG per batch row, Whh rows register-cached fp16 ----------------
__global__ __launch_bounds__(768, 3) void k_gru(const f16* gxt, const int* toks,
                                                const u32* whh, const float* bhh,
                                                const float* h0, f16* hout, int layer) {
    int b = blockIdx.x, tid = threadIdx.x, g = tid;
    u32 w[128];
    const uint4* wp = (const uint4*)(whh + g * 128);
#pragma unroll
    for (int k = 0; k < 32; k++) {
        uint4 t = wp[k];
        w[4*k] = t.x; w[4*k+1] = t.y; w[4*k+2] = t.z; w[4*k+3] = t.w;
    }
    float bn = (g >= 512) ? bhh[g] : 0.f;  // bhh_n kept out of gx fold (n = tanh(xn + r*(dot+bhh_n)))

    __shared__ __align__(16) u32 h2s[128];   // h as fp16 pairs
    __shared__ float hf[256];                // h master copy f32
    __shared__ float gl[768];                // per-gate dot results
    if (tid < 256) {
        float h = h0[b * 256 + tid];
        hf[tid] = h;
        ((f16*)h2s)[tid] = (f16)h;
    }
    __syncthreads();

    for (int t = 0; t < 64; t++) {
        const f16* gx;
        if (layer == 0) {
            int tok = (t == 0) ? 2 : toks[b * 64 + t - 1];
            gx = gxt + tok * 768;
        } else {
            gx = gxt + (t * 64 + b) * 768;
        }
        // issue gx loads early; latency hides under the dot phase
        float xr = 0.f, xz = 0.f, xn = 0.f;
        if (tid < 256) { xr = (float)gx[tid]; xz = (float)gx[tid + 256]; xn = (float)gx[tid + 512]; }

        float a0 = 0.f, a1 = 0.f, a2 = 0.f, a3 = 0.f;
        const uint4* hv = (const uint4*)h2s;
#pragma unroll
        for (int k = 0; k < 32; k++) {
            uint4 h4 = hv[k];
            a0 = dot2f(w[4*k],   h4.x, a0);
            a1 = dot2f(w[4*k+1], h4.y, a1);
            a2 = dot2f(w[4*k+2], h4.z, a2);
            a3 = dot2f(w[4*k+3], h4.w, a3);
        }
        gl[g] = (a0 + a1) + (a2 + a3) + bn;
        __syncthreads();
        if (tid < 256) {
            float r  = sigmoid_f(xr + gl[tid]);
            float zg = sigmoid_f(xz + gl[tid + 256]);
            float n  = tanh_f(xn + r * gl[tid + 512]);
            float hnew = (1.f - zg) * n + zg * hf[tid];
            hf[tid] = hnew;
            ((f16*)h2s)[tid] = (f16)hnew;
            int row = (layer == 0) ? (t * 64 + b) : (b * 64 + t);
            hout[row * 256 + tid] = (f16)hnew;
        }
        __syncthreads();
    }
}

// ---------------- gx1 = h1 @ Wih1.T + bih1 (+bhh1 for r,z) ----------------
__global__ __launch_bounds__(256) void k_gx1(const f16* h1, const u32* wih1,
                                             const float* bih1, const float* bhh1, f16* gx1) {
    int rb = blockIdx.x, row0 = rb * 8, tid = threadIdx.x;
    __shared__ __align__(16) u32 hs[8][128];
    const u32* src = (const u32*)h1 + row0 * 128;
    for (int i = tid; i < 1024; i += 256) hs[i >> 7][i & 127] = src[i];
    __syncthreads();
    for (int p = 0; p < 3; p++) {
        int g = tid + p * 256;
        float bias = bih1[g] + (g < 512 ? bhh1[g] : 0.f);
        float acc[8];
#pragma unroll
        for (int r = 0; r < 8; r++) acc[r] = bias;
        const u32* wrow = wih1 + g * 128;
#pragma unroll
        for (int c = 0; c < 8; c++) {
            u32 wreg[16];
            const uint4* wc = (const uint4*)(wrow + c * 16);
#pragma unroll
            for (int q = 0; q < 4; q++) {
                uint4 tt = wc[q];
                wreg[4*q] = tt.x; wreg[4*q+1] = tt.y; wreg[4*q+2] = tt.z; wreg[4*q+3] = tt.w;
            }
#pragma unroll
            for (int r = 0; r < 8; r++) {
                float a = acc[r];
#pragma unroll
                for (int k = 0; k < 16; k++) a = dot2f(wreg[k], hs[r][c * 16 + k], a);
                acc[r] = a;
            }
        }
        for (int r = 0; r < 8; r++) gx1[(row0 + r) * 768 + g] = (f16)acc[r];
    }
}

// ---------------- shared 16-row x 256-col fp16 GEMM helper (LDS rows, reg weights) ------------
template <int R>
DEV void lgemm(const u32 h[][128], const u32* wrow, float bias, float* acc) {
#pragma unroll
    for (int r = 0; r < R; r++) acc[r] = bias;
#pragma unroll
    for (int c = 0; c < 8; c++) {
        u32 wreg[16];
        const uint4* wc = (const uint4*)(wrow + c * 16);
#pragma unroll
        for (int q = 0; q < 4; q++) {
            uint4 t = wc[q];
            wreg[4*q] = t.x; wreg[4*q+1] = t.y; wreg[4*q+2] = t.z; wreg[4*q+3] = t.w;
        }
#pragma unroll
        for (int r = 0; r < R; r++) {
            float a = acc[r];
#pragma unroll
            for (int k = 0; k < 16; k++) a = dot2f(wreg[k], h[r][c * 16 + k], a);
            acc[r] = a;
        }
    }
}

// ---------------- node + stop heads ----------------
__global__ __launch_bounds__(256) void k_node_stop(const f16* hid,
        const u32* nhw1, const float* nhb1, const u32* nhw2, const float* nhb2,
        const u32* shw1, const float* shb1, const u32* shw2, const float* shb2,
        float* outn, float* outs) {
    int rb = blockIdx.x, row0 = rb * 16, tid = threadIdx.x;
    __shared__ __align__(16) u32 hs[16][128];
    __shared__ __align__(16) u32 t1[16][128];
    const u32* src = (const u32*)hid + row0 * 128;
    for (int i = tid; i < 2048; i += 256) hs[i >> 7][i & 127] = src[i];
    __syncthreads();
    float acc[16];
    lgemm<16>(hs, nhw1 + tid * 128, nhb1[tid], acc);
#pragma unroll
    for (int r = 0; r < 16; r++) ((f16*)t1[r])[tid] = (f16)fmaxf(acc[r], 0.f);
    __syncthreads();
    lgemm<16>(t1, nhw2 + tid * 128, nhb2[tid], acc);
#pragma unroll
    for (int r = 0; r < 16; r++) outn[(row0 + r) * 256 + tid] = acc[r];
    // stop head
    __shared__ __align__(16) u32 s1[16][64];
    if (tid < 128) {
        float a[16];
        lgemm<16>(hs, shw1 + tid * 128, shb1[tid], a);
#pragma unroll
        for (int r = 0; r < 16; r++) ((f16*)s1[r])[tid] = (f16)fmaxf(a[r], 0.f);
    }
    __syncthreads();
    if (tid < 16) {
        float a = shb2[0];
#pragma unroll
        for (int k = 0; k < 64; k++) a = dot2f(shw2[k], s1[tid][k], a);
        outs[row0 + tid] = a;
    }
}

// ---------------- hk/hq with combined weights ----------------
__global__ __launch_bounds__(256) void k_kq(const f16* hid, const u32* wkc, const u32* wqc,
                                            const float* bkc, const float* bqc,
                                            f16* hk, f16* hq) {
    int rb = blockIdx.x, row0 = rb * 16, tid = threadIdx.x;
    __shared__ __align__(16) u32 hs[16][128];
    const u32* src = (const u32*)hid + row0 * 128;
    for (int i = tid; i < 2048; i += 256) hs[i >> 7][i & 127] = src[i];
    __syncthreads();
    float acc[16];
    lgemm<16>(hs, wkc + tid * 128, bkc[tid], acc);
#pragma unroll
    for (int r = 0; r < 16; r++) hk[(row0 + r) * 256 + tid] = (f16)acc[r];
    lgemm<16>(hs, wqc + tid * 128, bqc[tid], acc);
#pragma unroll
    for (int r = 0; r < 16; r++) hq[(row0 + r) * 256 + tid] = (f16)acc[r];
}

// ---------------- edge logits: relu(hk_i + hq_j) . w2 + b2 ----------------
__global__ __launch_bounds__(256) void k_edge(const f16* hk, const f16* hq, const u32* w2,
                                              const float* ehb2, const int* mask,
                                              float* oute) {
    int bidx = blockIdx.x, b = bidx >> 2, itile = (bidx & 3) * 16, tid = threadIdx.x;
    __shared__ __align__(16) u32 hqs[64][128];  // XOR-swizzled on 16B slots by row&31
    __shared__ __align__(16) u32 hks[16][128];
    __shared__ __align__(16) u32 w2s[128];
    for (int i = tid; i < 8192; i += 256) {
        int row = i >> 7, dw = i & 127;
        u32 v = ((const u32*)hq)[(b * 64 + row) * 128 + dw];
        int slot = (dw >> 2) ^ (row & 31);
        hqs[row][(slot << 2) | (dw & 3)] = v;
    }
    for (int i = tid; i < 2048; i += 256) {
        int row = i >> 7, dw = i & 127;
        hks[row][dw] = ((const u32*)hk)[(b * 64 + itile + row) * 128 + dw];
    }
    if (tid < 128) w2s[tid] = w2[tid];
    __syncthreads();

    int wv = tid >> 6, j = tid & 63;
    bool mj = mask[b * 64 + j] != 0;
    float b2 = ehb2[0];
    for (int il = 0; il < 4; il++) {
        int ir = wv * 4 + il, i = itile + ir;
        bool mi = mask[b * 64 + i] != 0;
        float acc = 0.f;
#pragma unroll
        for (int s = 0; s < 32; s++) {
            uint4 a = *(const uint4*)&hks[ir][s << 2];
            uint4 q = *(const uint4*)&hqs[j][(s ^ (j & 31)) << 2];
            uint4 ww = *(const uint4*)&w2s[s << 2];
            acc = dot2f(addrelu2(a.x, q.x), ww.x, acc);
            acc = dot2f(addrelu2(a.y, q.y), ww.y, acc);
            acc = dot2f(addrelu2(a.z, q.z), ww.z, acc);
            acc = dot2f(addrelu2(a.w, q.w), ww.w, acc);
        }
        float out = acc + b2;
        if (!(mi && mj)) out = -INFINITY;
        oute[(b * 64 + i) * 64 + j] = out;
    }
}

// ---------------- host ----------------
extern "C" void kernel_launch(void* const* d_in, const int* in_sizes, int n_in,
                              void* d_out, int out_size, void* d_ws, size_t ws_size,
                              hipStream_t stream) {
    (void)in_sizes; (void)n_in; (void)out_size; (void)ws_size;
    const float* z      = (const float*)d_in[0];
    const int*   toks   = (const int*)d_in[1];
    const int*   mask   = (const int*)d_in[2];
    const float* l2hW1 = (const float*)d_in[3];
    const float* l2hb1 = (const float*)d_in[4];
    const float* l2hW2 = (const float*)d_in[5];
    const float* l2hb2 = (const float*)d_in[6];
    const float* emb   = (const float*)d_in[7];
    const float* wih0  = (const float*)d_in[8];
    const float* whh0  = (const float*)d_in[9];
    const float* bih0  = (const float*)d_in[10];
    const float* bhh0  = (const float*)d_in[11];
    const float* wih1  = (const float*)d_in[12];
    const float* whh1  = (const float*)d_in[13];
    const float* bih1  = (const float*)d_in[14];
    const float* bhh1  = (const float*)d_in[15];
    const float* nhW1  = (const float*)d_in[16];
    const float* nhb1  = (const float*)d_in[17];
    const float* nhW2  = (const float*)d_in[18];
    const float* nhb2  = (const float*)d_in[19];
    const float* ekW   = (const float*)d_in[20];
    const float* ekb   = (const float*)d_in[21];
    const float* eqW   = (const float*)d_in[22];
    const float* eqb   = (const float*)d_in[23];
    const float* ehW1  = (const float*)d_in[24];
    const float* ehb1  = (const float*)d_in[25];
    const float* ehW2  = (const float*)d_in[26];
    const float* ehb2  = (const float*)d_in[27];
    const float* shW1  = (const float*)d_in[28];
    const float* shb1  = (const float*)d_in[29];
    const float* shW2  = (const float*)d_in[30];
    const float* shb2  = (const float*)d_in[31];

    char* ws = (char*)d_ws;
    f16* gxt0  = (f16*)(ws + WS_GXT0);
    f16* whh0h = (f16*)(ws + WS_WHH0);
    f16* whh1h = (f16*)(ws + WS_WHH1);
    f16* wih1h = (f16*)(ws + WS_WIH1);
    f16* nhw1h = (f16*)(ws + WS_NHW1);
    f16* nhw2h = (f16*)(ws + WS_NHW2);
    f16* shw1h = (f16*)(ws + WS_SHW1);
    f16* shw2h = (f16*)(ws + WS_SHW2);
    f16* ehw2h = (f16*)(ws + WS_EHW2);
    f16* wkc   = (f16*)(ws + WS_WKC);
    f16* wqc   = (f16*)(ws + WS_WQC);
    float* bkc = (float*)(ws + WS_BKC);
    float* bqc = (float*)(ws + WS_BQC);
    float* h0w = (float*)(ws + WS_H0);
    f16* h1w   = (f16*)(ws + WS_H1);
    f16* gx1w  = (f16*)(ws + WS_GX1);
    f16* hidw  = (f16*)(ws + WS_HID);
    f16* hkw   = (f16*)(ws + WS_HK);
    f16* hqw   = (f16*)(ws + WS_HQ);

    float* outn = (float*)d_out;
    float* oute = (float*)d_out + 1048576;
    float* outs = (float*)d_out + 1310720;

    ConvArgs ca;
    ca.src[0] = whh0; ca.dst[0] = whh0h; ca.cnt[0] = 196608;
    ca.src[1] = whh1; ca.dst[1] = whh1h; ca.cnt[1] = 196608;
    ca.src[2] = wih1; ca.dst[2] = wih1h; ca.cnt[2] = 196608;
    ca.src[3] = nhW1; ca.dst[3] = nhw1h; ca.cnt[3] = 65536;
    ca.src[4] = nhW2; ca.dst[4] = nhw2h; ca.cnt[4] = 65536;
    ca.src[5] = shW1; ca.dst[5] = shw1h; ca.cnt[5] = 32768;
    ca.src[6] = shW2; ca.dst[6] = shw2h; ca.cnt[6] = 128;
    ca.src[7] = ehW2; ca.dst[7] = ehw2h; ca.cnt[7] = 256;

    k_convert<<<2946, 256, 0, stream>>>(ca);
    k_gxt0<<<256, 256, 0, stream>>>(emb, wih0, bih0, bhh0, gxt0);
    k_h0<<<64, 256, 0, stream>>>(z, l2hW1, l2hb1, l2hW2, l2hb2, h0w);
    k_wkq<<<512, 256, 0, stream>>>(ehW1, ekW, eqW, ekb, eqb, ehb1, wkc, wqc, bkc, bqc);
    k_gru<<<64, 768, 0, stream>>>(gxt0, toks, (const u32*)whh0h, bhh0, h0w, h1w, 0);
    k_gx1<<<512, 256, 0, stream>>>(h1w, (const u32*)wih1h, bih1, bhh1, gx1w);
    k_gru<<<64, 768, 0, stream>>>(gx1w, nullptr, (const u32*)whh1h, bhh1, h0w, hidw, 1);
    k_node_stop<<<256, 256, 0, stream>>>(hidw, (const u32*)nhw1h, nhb1, (const u32*)nhw2h, nhb2,
                                         (const u32*)shw1h, shb1, (const u32*)shw2h, shb2,
                                         outn, outs);
    k_kq<<<256, 256, 0, stream>>>(hidw, (const u32*)wkc, (const u32*)wqc, bkc, bqc, hkw, hqw);
    k_edge<<<256, 256, 0, stream>>>(hkw, hqw, (const u32*)ehw2h, ehb2, mask, oute);
}

// Round 3
// 316.916 us; speedup vs baseline: 3.2457x; 3.2457x over previous
//
#include <hip/hip_runtime.h>
#include <hip/hip_fp16.h>

// Problem dims (fixed): B=64, N=T=64, L=128, H=256, V=256, G=3H=768
typedef _Float16 f16;
typedef _Float16 f16x2 __attribute__((ext_vector_type(2)));
typedef unsigned int u32;

#define DEV static __device__ __forceinline__

DEV float dot2f(u32 a, u32 b, float c) {
#if __has_builtin(__builtin_amdgcn_fdot2)
    return __builtin_amdgcn_fdot2(__builtin_bit_cast(f16x2, a),
                                  __builtin_bit_cast(f16x2, b), c, false);
#else
    f16x2 x = __builtin_bit_cast(f16x2, a), y = __builtin_bit_cast(f16x2, b);
    return c + (float)x[0] * (float)y[0] + (float)x[1] * (float)y[1];
#endif
}

DEV float rcp_fast(float x) {
#if __has_builtin(__builtin_amdgcn_rcpf)
    return __builtin_amdgcn_rcpf(x);
#else
    return 1.f / x;
#endif
}
DEV float sigmoid_f(float x) { return rcp_fast(1.f + __expf(-x)); }
DEV float tanh_f(float x)    { return 1.f - 2.f * rcp_fast(1.f + __expf(2.f * x)); }

DEV u32 addrelu2(u32 a, u32 b) {  // fp16x2 (a+b) then relu
    f16x2 x = __builtin_bit_cast(f16x2, a) + __builtin_bit_cast(f16x2, b);
    f16x2 z = {};
    x = __builtin_elementwise_max(x, z);
    return __builtin_bit_cast(u32, x);
}

// ---------------- workspace layout (bytes) ----------------
#define WS_GXT0  0u          // 256*768 f16 token->gate table (layer0, biases folded)
#define WS_WHH0  393216u     // 768*256 f16
#define WS_WHH1  786432u
#define WS_WIH1  1179648u
#define WS_NHW1  1572864u    // 256*256 f16
#define WS_NHW2  1703936u
#define WS_SHW1  1835008u    // 128*256 f16
#define WS_SHW2  1900544u    // 128 f16
#define WS_EHW2  1900800u    // 256 f16
#define WS_WKC   1901312u    // 256*256 f16 combined W1k@ek_W
#define WS_WQC   2032384u
#define WS_BKC   2163456u    // 256 f32 (includes eh_b1)
#define WS_BQC   2164480u
#define WS_H0    2165504u    // 64*256 f32
#define WS_H1    2231040u    // 64*64*256 f16, (t,b,c)
#define WS_GX1   4328192u    // 4096*768 f16, (t*64+b, g)
#define WS_HID   10619648u   // 64*64*256 f16, (b,t,c)
#define WS_HK    12716800u   // 4096*256 f16
#define WS_HQ    14813952u

// ---------------- fp32 -> fp16 weight conversion ----------------
struct ConvArgs { const float* src[8]; f16* dst[8]; int cnt[8]; };

__global__ void k_convert(ConvArgs a) {
    int idx = blockIdx.x * 256 + threadIdx.x;
#pragma unroll
    for (int s = 0; s < 8; s++) {
        if (idx < a.cnt[s]) { a.dst[s][idx] = (f16)a.src[s][idx]; return; }
        idx -= a.cnt[s];
    }
}

// ---------------- gxt0 table: emb @ Wih0.T + bih0 (+bhh0 for r,z) ----------------
__global__ __launch_bounds__(256) void k_gxt0(const float* emb, const float* wih0,
                                              const float* bih0, const float* bhh0,
                                              f16* gxt0) {
    int v = blockIdx.x, tid = threadIdx.x;
    __shared__ float es[256];
    es[tid] = emb[v * 256 + tid];
    __syncthreads();
#pragma unroll 1
    for (int p = 0; p < 3; p++) {
        int g = tid + p * 256;
        const float4* w = (const float4*)(wih0 + g * 256);
        float acc = bih0[g] + (g < 512 ? bhh0[g] : 0.f);
        for (int k = 0; k < 64; k++) {
            float4 wv = w[k];
            acc += es[4*k]*wv.x + es[4*k+1]*wv.y + es[4*k+2]*wv.z + es[4*k+3]*wv.w;
        }
        gxt0[v * 768 + g] = (f16)acc;
    }
}

// ---------------- h0 = relu(z@W1.T+b1)@W2.T+b2 ----------------
__global__ __launch_bounds__(256) void k_h0(const float* z, const float* w1, const float* b1,
                                            const float* w2, const float* b2, float* h0) {
    int b = blockIdx.x, tid = threadIdx.x;
    __shared__ float zs[128];
    __shared__ float t1[256];
    if (tid < 128) zs[tid] = z[b * 128 + tid];
    __syncthreads();
    const float4* w = (const float4*)(w1 + tid * 128);
    float acc = b1[tid];
    for (int k = 0; k < 32; k++) {
        float4 wv = w[k];
        acc += zs[4*k]*wv.x + zs[4*k+1]*wv.y + zs[4*k+2]*wv.z + zs[4*k+3]*wv.w;
    }
    t1[tid] = fmaxf(acc, 0.f);
    __syncthreads();
    const float4* ww = (const float4*)(w2 + tid * 256);
    float a2 = b2[tid];
    for (int k = 0; k < 64; k++) {
        float4 wv = ww[k];
        a2 += t1[4*k]*wv.x + t1[4*k+1]*wv.y + t1[4*k+2]*wv.z + t1[4*k+3]*wv.w;
    }
    h0[b * 256 + tid] = a2;
}

// ---------------- combined edge weights: Wk_c = W1k@ek_W etc ----------------
__global__ __launch_bounds__(256) void k_wkq(const float* ehW1, const float* ekW, const float* eqW,
                                             const float* ekb, const float* eqb, const float* ehb1,
                                             f16* wkc, f16* wqc, float* bkc, float* bqc) {
    int blk = blockIdx.x, which = blk >> 8, o = blk & 255, tid = threadIdx.x;
    __shared__ float w1s[256];
    w1s[tid] = ehW1[o * 512 + (which ? 256 : 0) + tid];
    __syncthreads();
    const float* m = which ? eqW : ekW;
    float acc = 0.f;
    for (int mm = 0; mm < 256; mm++) acc += w1s[mm] * m[mm * 256 + tid];
    (which ? wqc : wkc)[o * 256 + tid] = (f16)acc;
    if (tid == 0) {
        const float* bb = which ? eqb : ekb;
        float s = which ? 0.f : ehb1[o];   // fold eh_b1 into k-side bias
        for (int mm = 0; mm < 256; mm++) s += w1s[mm] * bb[mm];
        (which ? bqc : bkc)[o] = s;
    }
}

// ---------------- GRU layer: 1 WG per batch row, Whh rows register-cached fp16 ----------------
__global__ __launch_bounds__(768, 3) void k_gru(const f16* gxt, const int* toks,
                                                const u32* whh, const float* bhh,
                                                const float* h0, f16* hout, int layer) {
    int b = blockIdx.x, tid = threadIdx.x, g = tid;
    u32 w[128];
    const uint4* wp = (const uint4*)(whh + g * 128);
#pragma unroll
    for (int k = 0; k < 32; k++) {
        uint4 t = wp[k];
        w[4*k] = t.x; w[4*k+1] = t.y; w[4*k+2] = t.z; w[4*k+3] = t.w;
    }
    float bn = (g >= 512) ? bhh[g] : 0.f;  // bhh_n kept out of gx fold (n = tanh(xn + r*(dot+bhh_n)))

    __shared__ __align__(16) u32 h2s[128];   // h as fp16 pairs
    __shared__ float hf[256];                // h master copy f32
    __shared__ float gl[768];                // per-gate dot results
    if (tid < 256) {
        float h = h0[b * 256 + tid];
        hf[tid] = h;
        ((f16*)h2s)[tid] = (f16)h;
    }
    __syncthreads();

    for (int t = 0; t < 64; t++) {
        const f16* gx;
        if (layer == 0) {
            int tok = (t == 0) ? 2 : toks[b * 64 + t - 1];
            gx = gxt + tok * 768;
        } else {
            gx = gxt + (t * 64 + b) * 768;
        }
        // issue gx loads early; latency hides under the dot phase
        float xr = 0.f, xz = 0.f, xn = 0.f;
        if (tid < 256) { xr = (float)gx[tid]; xz = (float)gx[tid + 256]; xn = (float)gx[tid + 512]; }

        float a0 = 0.f, a1 = 0.f, a2 = 0.f, a3 = 0.f;
        const uint4* hv = (const uint4*)h2s;
#pragma unroll
        for (int k = 0; k < 32; k++) {
            uint4 h4 = hv[k];
            a0 = dot2f(w[4*k],   h4.x, a0);
            a1 = dot2f(w[4*k+1], h4.y, a1);
            a2 = dot2f(w[4*k+2], h4.z, a2);
            a3 = dot2f(w[4*k+3], h4.w, a3);
        }
        gl[g] = (a0 + a1) + (a2 + a3) + bn;
        __syncthreads();
        if (tid < 256) {
            float r  = sigmoid_f(xr + gl[tid]);
            float zg = sigmoid_f(xz + gl[tid + 256]);
            float n  = tanh_f(xn + r * gl[tid + 512]);
            float hnew = (1.f - zg) * n + zg * hf[tid];
            hf[tid] = hnew;
            ((f16*)h2s)[tid] = (f16)hnew;
            int row = (layer == 0) ? (t * 64 + b) : (b * 64 + t);
            hout[row * 256 + tid] = (f16)hnew;
        }
        __syncthreads();
    }
}

// ---------------- shared GEMM helper: software-pipelined, unroll-1 c-loop ------------
// One 16-dword weight chunk + one prefetch chunk live (~70 VGPR, no spill).
// Acts read as b128 broadcasts from LDS.
template <int R>
DEV void lgemm(const u32 h[][128], const u32* wrow, float bias, float* acc) {
    const uint4* wc = (const uint4*)wrow;
#pragma unroll
    for (int r = 0; r < R; r++) acc[r] = bias;
    uint4 w0 = wc[0], w1 = wc[1], w2 = wc[2], w3 = wc[3];
#pragma unroll 1
    for (int c = 0; c < 8; c++) {
        int cn = (c + 1) & 7;  // last iter re-reads chunk 0 (discarded, in-bounds)
        uint4 n0 = wc[4*cn], n1 = wc[4*cn+1], n2 = wc[4*cn+2], n3 = wc[4*cn+3];
#pragma unroll
        for (int r = 0; r < R; r++) {
            const uint4* hp = (const uint4*)&h[r][c * 16];
            uint4 h0 = hp[0], h1 = hp[1], h2 = hp[2], h3 = hp[3];
            float a = acc[r];
            a = dot2f(w0.x, h0.x, a); a = dot2f(w0.y, h0.y, a);
            a = dot2f(w0.z, h0.z, a); a = dot2f(w0.w, h0.w, a);
            a = dot2f(w1.x, h1.x, a); a = dot2f(w1.y, h1.y, a);
            a = dot2f(w1.z, h1.z, a); a = dot2f(w1.w, h1.w, a);
            a = dot2f(w2.x, h2.x, a); a = dot2f(w2.y, h2.y, a);
            a = dot2f(w2.z, h2.z, a); a = dot2f(w2.w, h2.w, a);
            a = dot2f(w3.x, h3.x, a); a = dot2f(w3.y, h3.y, a);
            a = dot2f(w3.z, h3.z, a); a = dot2f(w3.w, h3.w, a);
            acc[r] = a;
        }
        w0 = n0; w1 = n1; w2 = n2; w3 = n3;
    }
}

// ---------------- gx1 = h1 @ Wih1.T + bih1 (+bhh1 for r,z) ----------------
__global__ __launch_bounds__(256) void k_gx1(const f16* h1, const u32* wih1,
                                             const float* bih1, const float* bhh1, f16* gx1) {
    int rb = blockIdx.x, row0 = rb * 8, tid = threadIdx.x;
    __shared__ __align__(16) u32 hs[8][128];
    const u32* src = (const u32*)h1 + row0 * 128;
    for (int i = tid; i < 1024; i += 256) hs[i >> 7][i & 127] = src[i];
    __syncthreads();
#pragma unroll 1
    for (int p = 0; p < 3; p++) {
        int g = tid + p * 256;
        float bias = bih1[g] + (g < 512 ? bhh1[g] : 0.f);
        float acc[8];
        lgemm<8>(hs, wih1 + g * 128, bias, acc);
#pragma unroll
        for (int r = 0; r < 8; r++) gx1[(row0 + r) * 768 + g] = (f16)acc[r];
    }
}

// ---------------- node + stop heads ----------------
__global__ __launch_bounds__(256) void k_node_stop(const f16* hid,
        const u32* nhw1, const float* nhb1, const u32* nhw2, const float* nhb2,
        const u32* shw1, const float* shb1, const u32* shw2, const float* shb2,
        float* outn, float* outs) {
    int rb = blockIdx.x, row0 = rb * 16, tid = threadIdx.x;
    __shared__ __align__(16) u32 hs[16][128];
    __shared__ __align__(16) u32 t1[16][128];
    const u32* src = (const u32*)hid + row0 * 128;
    for (int i = tid; i < 2048; i += 256) hs[i >> 7][i & 127] = src[i];
    __syncthreads();
    float acc[16];
    lgemm<16>(hs, nhw1 + tid * 128, nhb1[tid], acc);
#pragma unroll
    for (int r = 0; r < 16; r++) ((f16*)t1[r])[tid] = (f16)fmaxf(acc[r], 0.f);
    __syncthreads();
    lgemm<16>(t1, nhw2 + tid * 128, nhb2[tid], acc);
#pragma unroll
    for (int r = 0; r < 16; r++) outn[(row0 + r) * 256 + tid] = acc[r];
    // stop head
    __shared__ __align__(16) u32 s1[16][64];
    if (tid < 128) {
        float a[16];
        lgemm<16>(hs, shw1 + tid * 128, shb1[tid], a);
#pragma unroll
        for (int r = 0; r < 16; r++) ((f16*)s1[r])[tid] = (f16)fmaxf(a[r], 0.f);
    }
    __syncthreads();
    if (tid < 16) {
        float a = shb2[0];
#pragma unroll
        for (int k = 0; k < 64; k++) a = dot2f(shw2[k], s1[tid][k], a);
        outs[row0 + tid] = a;
    }
}

// ---------------- hk/hq with combined weights ----------------
__global__ __launch_bounds__(256) void k_kq(const f16* hid, const u32* wkc, const u32* wqc,
                                            const float* bkc, const float* bqc,
                                            f16* hk, f16* hq) {
    int rb = blockIdx.x, row0 = rb * 16, tid = threadIdx.x;
    __shared__ __align__(16) u32 hs[16][128];
    const u32* src = (const u32*)hid + row0 * 128;
    for (int i = tid; i < 2048; i += 256) hs[i >> 7][i & 127] = src[i];
    __syncthreads();
    float acc[16];
    lgemm<16>(hs, wkc + tid * 128, bkc[tid], acc);
#pragma unroll
    for (int r = 0; r < 16; r++) hk[(row0 + r) * 256 + tid] = (f16)acc[r];
    float acc2[16];
    lgemm<16>(hs, wqc + tid * 128, bqc[tid], acc2);
#pragma unroll
    for (int r = 0; r < 16; r++) hq[(row0 + r) * 256 + tid] = (f16)acc2[r];
}

// ---------------- edge logits: relu(hk_i + hq_j) . w2 + b2 ----------------
__global__ __launch_bounds__(256) void k_edge(const f16* hk, const f16* hq, const u32* w2,
                                              const float* ehb2, const int* mask,
                                              float* oute) {
    int bidx = blockIdx.x, b = bidx >> 2, itile = (bidx & 3) * 16, tid = threadIdx.x;
    __shared__ __align__(16) u32 hqs[64][128];  // XOR-swizzled on 16B slots by row&31
    __shared__ __align__(16) u32 hks[16][128];
    __shared__ __align__(16) u32 w2s[128];
    for (int i = tid; i < 8192; i += 256) {
        int row = i >> 7, dw = i & 127;
        u32 v = ((const u32*)hq)[(b * 64 + row) * 128 + dw];
        int slot = (dw >> 2) ^ (row & 31);
        hqs[row][(slot << 2) | (dw & 3)] = v;
    }
    for (int i = tid; i < 2048; i += 256) {
        int row = i >> 7, dw = i & 127;
        hks[row][dw] = ((const u32*)hk)[(b * 64 + itile + row) * 128 + dw];
    }
    if (tid < 128) w2s[tid] = w2[tid];
    __syncthreads();

    int wv = tid >> 6, j = tid & 63;
    bool mj = mask[b * 64 + j] != 0;
    float b2 = ehb2[0];
#pragma unroll 1
    for (int il = 0; il < 4; il++) {
        int ir = wv * 4 + il, i = itile + ir;
        bool mi = mask[b * 64 + i] != 0;
        float acc = 0.f;
#pragma unroll
        for (int s = 0; s < 32; s++) {
            uint4 a = *(const uint4*)&hks[ir][s << 2];
            uint4 q = *(const uint4*)&hqs[j][(s ^ (j & 31)) << 2];
            uint4 ww = *(const uint4*)&w2s[s << 2];
            acc = dot2f(addrelu2(a.x, q.x), ww.x, acc);
            acc = dot2f(addrelu2(a.y, q.y), ww.y, acc);
            acc = dot2f(addrelu2(a.z, q.z), ww.z, acc);
            acc = dot2f(addrelu2(a.w, q.w), ww.w, acc);
        }
        float out = acc + b2;
        if (!(mi && mj)) out = -INFINITY;
        oute[(b * 64 + i) * 64 + j] = out;
    }
}

// ---------------- host ----------------
extern "C" void kernel_launch(void* const* d_in, const int* in_sizes, int n_in,
                              void* d_out, int out_size, void* d_ws, size_t ws_size,
                              hipStream_t stream) {
    (void)in_sizes; (void)n_in; (void)out_size; (void)ws_size;
    const float* z      = (const float*)d_in[0];
    const int*   toks   = (const int*)d_in[1];
    const int*   mask   = (const int*)d_in[2];
    const float* l2hW1 = (const float*)d_in[3];
    const float* l2hb1 = (const float*)d_in[4];
    const float* l2hW2 = (const float*)d_in[5];
    const float* l2hb2 = (const float*)d_in[6];
    const float* emb   = (const float*)d_in[7];
    const float* wih0  = (const float*)d_in[8];
    const float* whh0  = (const float*)d_in[9];
    const float* bih0  = (const float*)d_in[10];
    const float* bhh0  = (const float*)d_in[11];
    const float* wih1  = (const float*)d_in[12];
    const float* whh1  = (const float*)d_in[13];
    const float* bih1  = (const float*)d_in[14];
    const float* bhh1  = (const float*)d_in[15];
    const float* nhW1  = (const float*)d_in[16];
    const float* nhb1  = (const float*)d_in[17];
    const float* nhW2  = (const float*)d_in[18];
    const float* nhb2  = (const float*)d_in[19];
    const float* ekW   = (const float*)d_in[20];
    const float* ekb   = (const float*)d_in[21];
    const float* eqW   = (const float*)d_in[22];
    const float* eqb   = (const float*)d_in[23];
    const float* ehW1  = (const float*)d_in[24];
    const float* ehb1  = (const float*)d_in[25];
    const float* ehW2  = (const float*)d_in[26];
    const float* ehb2  = (const float*)d_in[27];
    const float* shW1  = (const float*)d_in[28];
    const float* shb1  = (const float*)d_in[29];
    const float* shW2  = (const float*)d_in[30];
    const float* shb2  = (const float*)d_in[31];

    char* ws = (char*)d_ws;
    f16* gxt0  = (f16*)(ws + WS_GXT0);
    f16* whh0h = (f16*)(ws + WS_WHH0);
    f16* whh1h = (f16*)(ws + WS_WHH1);
    f16* wih1h = (f16*)(ws + WS_WIH1);
    f16* nhw1h = (f16*)(ws + WS_NHW1);
    f16* nhw2h = (f16*)(ws + WS_NHW2);
    f16* shw1h = (f16*)(ws + WS_SHW1);
    f16* shw2h = (f16*)(ws + WS_SHW2);
    f16* ehw2h = (f16*)(ws + WS_EHW2);
    f16* wkc   = (f16*)(ws + WS_WKC);
    f16* wqc   = (f16*)(ws + WS_WQC);
    float* bkc = (float*)(ws + WS_BKC);
    float* bqc = (float*)(ws + WS_BQC);
    float* h0w = (float*)(ws + WS_H0);
    f16* h1w   = (f16*)(ws + WS_H1);
    f16* gx1w  = (f16*)(ws + WS_GX1);
    f16* hidw  = (f16*)(ws + WS_HID);
    f16* hkw   = (f16*)(ws + WS_HK);
    f16* hqw   = (f16*)(ws + WS_HQ);

    float* outn = (float*)d_out;
    float* oute = (float*)d_out + 1048576;
    float* outs = (float*)d_out + 1310720;

    ConvArgs ca;
    ca.src[0] = whh0; ca.dst[0] = whh0h; ca.cnt[0] = 196608;
    ca.src[1] = whh1; ca.dst[1] = whh1h; ca.cnt[1] = 196608;
    ca.src[2] = wih1; ca.dst[2] = wih1h; ca.cnt[2] = 196608;
    ca.src[3] = nhW1; ca.dst[3] = nhw1h; ca.cnt[3] = 65536;
    ca.src[4] = nhW2; ca.dst[4] = nhw2h; ca.cnt[4] = 65536;
    ca.src[5] = shW1; ca.dst[5] = shw1h; ca.cnt[5] = 32768;
    ca.src[6] = shW2; ca.dst[6] = shw2h; ca.cnt[6] = 128;
    ca.src[7] = ehW2; ca.dst[7] = ehw2h; ca.cnt[7] = 256;

    k_convert<<<2946, 256, 0, stream>>>(ca);
    k_gxt0<<<256, 256, 0, stream>>>(emb, wih0, bih0, bhh0, gxt0);
    k_h0<<<64, 256, 0, stream>>>(z, l2hW1, l2hb1, l2hW2, l2hb2, h0w);
    k_wkq<<<512, 256, 0, stream>>>(ehW1, ekW, eqW, ekb, eqb, ehb1, wkc, wqc, bkc, bqc);
    k_gru<<<64, 768, 0, stream>>>(gxt0, toks, (const u32*)whh0h, bhh0, h0w, h1w, 0);
    k_gx1<<<512, 256, 0, stream>>>(h1w, (const u32*)wih1h, bih1, bhh1, gx1w);
    k_gru<<<64, 768, 0, stream>>>(gx1w, nullptr, (const u32*)whh1h, bhh1, h0w, hidw, 1);
    k_node_stop<<<256, 256, 0, stream>>>(hidw, (const u32*)nhw1h, nhb1, (const u32*)nhw2h, nhb2,
                                         (const u32*)shw1h, shb1, (const u32*)shw2h, shb2,
                                         outn, outs);
    k_kq<<<256, 256, 0, stream>>>(hidw, (const u32*)wkc, (const u32*)wqc, bkc, bqc, hkw, hqw);
    k_edge<<<256, 256, 0, stream>>>(hkw, hqw, (const u32*)ehw2h, ehb2, mask, oute);
}